// Round 1
// baseline (164.436 us; speedup 1.0000x reference)
//
#include <hip/hip_runtime.h>
#include <hip/hip_bf16.h>

#define E_DIM 8192
#define L_DIM 1024
#define C2_DIM 240
#define KSPLIT 16
#define KCHUNK (E_DIM / KSPLIT)   // 512

// Scratch layout inside d_out (floats):
//   part[KSPLIT][C2][L] at offset 0          (16*240*1024 = 3,932,160)
//   edge[C2][L]         at offset 4,194,304  (245,760)
// Both regions are fully overwritten by the final broadcast kernel.
// d_ws: colbuf[L] floats at offset 0.

// ---------------- Stage 1: K-split partial GEMM (fp32 VALU) ----------------
// grid (4 ntiles, 6 mtiles, KSPLIT), block 256 = 4 waves.
// Each wave: 10 m-rows x 256 n-cols; each lane: 10m x 4n accumulators.
__global__ __launch_bounds__(256) void k_gemm_part(
    const float* __restrict__ W, const float* __restrict__ A,
    float* __restrict__ part)
{
  const int lane = threadIdx.x & 63;
  const int wv   = __builtin_amdgcn_readfirstlane(threadIdx.x >> 6);
  const int n0 = blockIdx.x * 256 + lane * 4;
  const int m0 = blockIdx.y * 40 + wv * 10;
  const int k0 = blockIdx.z * KCHUNK;

  float acc[10][4];
#pragma unroll
  for (int i = 0; i < 10; ++i) {
    acc[i][0] = 0.f; acc[i][1] = 0.f; acc[i][2] = 0.f; acc[i][3] = 0.f;
  }

  const float* Abase = A + (size_t)k0 * L_DIM + n0;
  const float* Wbase = W + (size_t)m0 * E_DIM + k0;

  for (int kk = 0; kk < KCHUNK; kk += 4) {
    float4 b0 = *(const float4*)(Abase + (size_t)(kk + 0) * L_DIM);
    float4 b1 = *(const float4*)(Abase + (size_t)(kk + 1) * L_DIM);
    float4 b2 = *(const float4*)(Abase + (size_t)(kk + 2) * L_DIM);
    float4 b3 = *(const float4*)(Abase + (size_t)(kk + 3) * L_DIM);
#pragma unroll
    for (int mi = 0; mi < 10; ++mi) {
      float4 w = *(const float4*)(Wbase + (size_t)mi * E_DIM + kk);
      acc[mi][0] = fmaf(w.x, b0.x, fmaf(w.y, b1.x, fmaf(w.z, b2.x, fmaf(w.w, b3.x, acc[mi][0]))));
      acc[mi][1] = fmaf(w.x, b0.y, fmaf(w.y, b1.y, fmaf(w.z, b2.y, fmaf(w.w, b3.y, acc[mi][1]))));
      acc[mi][2] = fmaf(w.x, b0.z, fmaf(w.y, b1.z, fmaf(w.z, b2.z, fmaf(w.w, b3.z, acc[mi][2]))));
      acc[mi][3] = fmaf(w.x, b0.w, fmaf(w.y, b1.w, fmaf(w.z, b2.w, fmaf(w.w, b3.w, acc[mi][3]))));
    }
  }

#pragma unroll
  for (int mi = 0; mi < 10; ++mi) {
    float4 v = make_float4(acc[mi][0], acc[mi][1], acc[mi][2], acc[mi][3]);
    *(float4*)(part + ((size_t)blockIdx.z * C2_DIM + m0 + mi) * L_DIM + n0) = v;
  }
}

// ---------------- Stage 2a: reduce k-chunks, +bias, ReLU -------------------
// grid 960, block 256: one thread per (m, n) of [240][1024].
__global__ __launch_bounds__(256) void k_reduce_edge(
    const float* __restrict__ part, const float* __restrict__ b3,
    float* __restrict__ edge)
{
  const int gid = blockIdx.x * 256 + threadIdx.x;   // 0 .. 245759
  const int m = gid >> 10;
  const int n = gid & 1023;
  float s = 0.f;
#pragma unroll
  for (int ks = 0; ks < KSPLIT; ++ks)
    s += part[((size_t)ks * C2_DIM + m) * L_DIM + n];
  s += b3[m];
  edge[gid] = s > 0.f ? s : 0.f;
}

// ---------------- Stage 2b: conv4 dot, sigmoid, column sum -----------------
// grid 16, block 256: block handles 64 n; 4 m-groups of 60 reduced via LDS.
__global__ __launch_bounds__(256) void k_mask_colsum(
    const float* __restrict__ edge, const float* __restrict__ w4,
    const float* __restrict__ b4, float* __restrict__ colbuf)
{
  __shared__ float s_c4[4][64];
  __shared__ float s_cs[4][64];
  const int lane = threadIdx.x & 63;
  const int grp  = threadIdx.x >> 6;
  const int n = blockIdx.x * 64 + lane;

  float c4 = 0.f, cs = 0.f;
#pragma unroll 4
  for (int mi = 0; mi < 60; ++mi) {
    const int m = grp * 60 + mi;
    const float e = edge[(size_t)m * L_DIM + n];
    c4 = fmaf(w4[m], e, c4);
    cs += e;
  }
  s_c4[grp][lane] = c4;
  s_cs[grp][lane] = cs;
  __syncthreads();
  if (threadIdx.x < 64) {
    const float tc4 = s_c4[0][lane] + s_c4[1][lane] + s_c4[2][lane] + s_c4[3][lane] + b4[0];
    const float tcs = s_cs[0][lane] + s_cs[1][lane] + s_cs[2][lane] + s_cs[3][lane];
    const float mask = 1.f / (1.f + expf(-tc4));
    colbuf[n] = tcs * (1.f + mask) * (1.f / (float)L_DIM);
  }
}

// ---------------- Stage 3: broadcast to all nodes --------------------------
// grid 10000, block 256: one float4 per thread, 10,240,000 floats total.
__global__ __launch_bounds__(256) void k_broadcast(
    const float* __restrict__ colbuf, float4* __restrict__ out)
{
  const size_t idx = (size_t)blockIdx.x * 256 + threadIdx.x; // float4 index
  const int nq = (int)(idx & 255);                           // float4 within row
  const float4 v = *(const float4*)(colbuf + nq * 4);
  out[idx] = v;
}

extern "C" void kernel_launch(void* const* d_in, const int* in_sizes, int n_in,
                              void* d_out, int out_size, void* d_ws, size_t ws_size,
                              hipStream_t stream) {
  // setup_inputs order: x, edge_index, edge_attr, conv3_w, conv3_b, conv4_w, conv4_b
  const float* edge_attr = (const float*)d_in[2];   // [8192][1024]
  const float* w3        = (const float*)d_in[3];   // [240][8192]
  const float* b3        = (const float*)d_in[4];   // [240]
  const float* w4        = (const float*)d_in[5];   // [240]
  const float* b4        = (const float*)d_in[6];   // [1]

  float* out    = (float*)d_out;
  float* part   = out;                 // [KSPLIT][240][1024]
  float* edge   = out + 4194304;       // [240][1024]
  float* colbuf = (float*)d_ws;        // [1024]

  k_gemm_part  <<<dim3(4, 6, KSPLIT), 256, 0, stream>>>(w3, edge_attr, part);
  k_reduce_edge<<<dim3(960),          256, 0, stream>>>(part, b3, edge);
  k_mask_colsum<<<dim3(16),           256, 0, stream>>>(edge, w4, b4, colbuf);
  k_broadcast  <<<dim3(10000),        256, 0, stream>>>(colbuf, (float4*)out);
}

// Round 2
// 53.214 us; speedup vs baseline: 3.0901x; 3.0901x over previous
//
#include <hip/hip_runtime.h>
#include <hip/hip_bf16.h>

#define K_DIM 8192
#define L_DIM 1024
#define C2_DIM 240
#define BM 256
#define BN 128
#define BK 64
#define KCHUNK 256
#define KSPLIT 32                    // 8192 / 256
#define NSTEP (KCHUNK / BK)          // 4
#define PART_STRIDE (C2_DIM * L_DIM) // 245760 (per k-chunk, in elements)
#define EDGE_OFF 4000000             // float offset of edge[] inside d_out

typedef __attribute__((ext_vector_type(4))) float f32x4;
typedef __attribute__((ext_vector_type(8))) short bf16x8;
typedef __attribute__((ext_vector_type(4))) short bf16x4;

__device__ __forceinline__ unsigned short f2bf(float f) {
  unsigned u = __builtin_bit_cast(unsigned, f);
  u += 0x7fffu + ((u >> 16) & 1u);          // RTNE
  return (unsigned short)(u >> 16);
}
__device__ __forceinline__ float bf2f(unsigned short h) {
  unsigned u = ((unsigned)h) << 16;
  return __builtin_bit_cast(float, u);
}

// ---------------- Stage 1: bf16 MFMA K-split GEMM --------------------------
// C[240][1024] = W[240][8192] @ A[8192][1024], partials per k-chunk in bf16.
// grid (8 n-tiles, 32 k-chunks), block 512 = 8 waves (4 m-grps x 2 n-grps).
__global__ __launch_bounds__(512) void k_gemm(
    const float* __restrict__ Wm, const float* __restrict__ Am,
    unsigned short* __restrict__ part)
{
  __shared__ __align__(16) unsigned short sW[BM * BK]; // [m][k^swz] 32 KB
  __shared__ __align__(16) unsigned short sA[BN * BK]; // [n][k^swz] 16 KB

  const int t    = threadIdx.x;
  const int lane = t & 63;
  const int wid  = t >> 6;
  const int mgrp = wid & 3;      // 64-row m group
  const int ngrp = wid >> 2;     // 64-col n group
  const int n0b  = blockIdx.x * BN;
  const int kc0  = blockIdx.y * KCHUNK;
  const int l15  = lane & 15;
  const int lk8  = (lane >> 4) * 8;

  // staging assignment: W: thread -> (row sm, half skh); A: (k-quad sk, n-quad sn)
  const int sm  = t >> 1;          // 0..255
  const int skh = (t & 1) * 32;    // 0 / 32
  const int sn  = (t & 31) * 4;    // 0..124
  const int sk  = (t >> 5) * 4;    // 0..60

  f32x4 wreg[8], areg[4];
  f32x4 acc[4][4];
#pragma unroll
  for (int i = 0; i < 4; ++i)
#pragma unroll
    for (int j = 0; j < 4; ++j) acc[i][j] = (f32x4){0.f, 0.f, 0.f, 0.f};

  const float* wp = Wm + (size_t)sm * K_DIM + kc0 + skh;
  const float* ap = Am + (size_t)(kc0 + sk) * L_DIM + n0b + sn;
  const bool wok = (sm < C2_DIM);

  // prefetch step 0
#pragma unroll
  for (int j = 0; j < 8; ++j)
    wreg[j] = wok ? *(const f32x4*)(wp + 4 * j) : (f32x4){0.f, 0.f, 0.f, 0.f};
#pragma unroll
  for (int r = 0; r < 4; ++r)
    areg[r] = *(const f32x4*)(ap + (size_t)r * L_DIM);

  for (int s = 0; s < NSTEP; ++s) {
    // ---- convert + LDS write (waits on in-flight loads via vmcnt) ----
#pragma unroll
    for (int j = 0; j < 4; ++j) {
      f32x4 a = wreg[2 * j], b = wreg[2 * j + 1];
      bf16x8 v;
      v[0] = (short)f2bf(a[0]); v[1] = (short)f2bf(a[1]);
      v[2] = (short)f2bf(a[2]); v[3] = (short)f2bf(a[3]);
      v[4] = (short)f2bf(b[0]); v[5] = (short)f2bf(b[1]);
      v[6] = (short)f2bf(b[2]); v[7] = (short)f2bf(b[3]);
      *(bf16x8*)&sW[sm * BK + ((skh + 8 * j) ^ ((sm & 7) << 3))] = v;
    }
#pragma unroll
    for (int j = 0; j < 4; ++j) {
      int n = sn + j;
      bf16x4 v;
      v[0] = (short)f2bf(areg[0][j]); v[1] = (short)f2bf(areg[1][j]);
      v[2] = (short)f2bf(areg[2][j]); v[3] = (short)f2bf(areg[3][j]);
      *(bf16x4*)&sA[n * BK + (sk ^ ((n & 7) << 3))] = v;
    }
    __syncthreads();

    // ---- issue next step's global loads (overlap with MFMA below) ----
    if (s + 1 < NSTEP) {
      const float* wp2 = wp + (s + 1) * BK;
      const float* ap2 = ap + (size_t)(s + 1) * BK * L_DIM;
#pragma unroll
      for (int j = 0; j < 8; ++j)
        wreg[j] = wok ? *(const f32x4*)(wp2 + 4 * j) : (f32x4){0.f, 0.f, 0.f, 0.f};
#pragma unroll
      for (int r = 0; r < 4; ++r)
        areg[r] = *(const f32x4*)(ap2 + (size_t)r * L_DIM);
    }

    // ---- compute from LDS ----
#pragma unroll
    for (int kk = 0; kk < BK; kk += 32) {
      bf16x8 wf[4], af[4];
#pragma unroll
      for (int mt = 0; mt < 4; ++mt) {
        int m = mgrp * 64 + mt * 16 + l15;
        wf[mt] = *(const bf16x8*)&sW[m * BK + ((kk + lk8) ^ ((m & 7) << 3))];
      }
#pragma unroll
      for (int nt = 0; nt < 4; ++nt) {
        int n = ngrp * 64 + nt * 16 + l15;
        af[nt] = *(const bf16x8*)&sA[n * BK + ((kk + lk8) ^ ((n & 7) << 3))];
      }
#pragma unroll
      for (int mt = 0; mt < 4; ++mt)
#pragma unroll
        for (int nt = 0; nt < 4; ++nt)
          acc[mt][nt] = __builtin_amdgcn_mfma_f32_16x16x32_bf16(
              wf[mt], af[nt], acc[mt][nt], 0, 0, 0);
    }
    __syncthreads();
  }

  // ---- store bf16 partials ----
  unsigned short* pb = part + (size_t)blockIdx.y * PART_STRIDE;
#pragma unroll
  for (int mt = 0; mt < 4; ++mt) {
    int mbase = mgrp * 64 + mt * 16 + (lane >> 4) * 4;
#pragma unroll
    for (int r = 0; r < 4; ++r) {
      int m = mbase + r;
      if (m < C2_DIM) {
#pragma unroll
        for (int nt = 0; nt < 4; ++nt) {
          int n = n0b + ngrp * 64 + nt * 16 + l15;
          pb[(size_t)m * L_DIM + n] = f2bf(acc[mt][nt][r]);
        }
      }
    }
  }
}

// ---------------- Stage 2a: reduce k-chunks, +bias, ReLU -------------------
__global__ __launch_bounds__(256) void k_reduce(
    const unsigned short* __restrict__ part, const float* __restrict__ b3,
    float* __restrict__ edge)
{
  const int gid = blockIdx.x * 256 + threadIdx.x; // 0..245759
  const int m = gid >> 10;
  float s = 0.f;
#pragma unroll
  for (int kc = 0; kc < KSPLIT; ++kc)
    s += bf2f(part[(size_t)kc * PART_STRIDE + gid]);
  s += b3[m];
  edge[gid] = s > 0.f ? s : 0.f;
}

// ---------------- Stage 2b: conv4 dot, sigmoid, column sum -----------------
__global__ __launch_bounds__(256) void k_mask_colsum(
    const float* __restrict__ edge, const float* __restrict__ w4,
    const float* __restrict__ b4, float* __restrict__ colbuf)
{
  __shared__ float s_c4[4][64];
  __shared__ float s_cs[4][64];
  const int lane = threadIdx.x & 63;
  const int grp  = threadIdx.x >> 6;
  const int n = blockIdx.x * 64 + lane;

  float c4 = 0.f, cs = 0.f;
#pragma unroll 4
  for (int mi = 0; mi < 60; ++mi) {
    const int m = grp * 60 + mi;
    const float e = edge[(size_t)m * L_DIM + n];
    c4 = fmaf(w4[m], e, c4);
    cs += e;
  }
  s_c4[grp][lane] = c4;
  s_cs[grp][lane] = cs;
  __syncthreads();
  if (threadIdx.x < 64) {
    const float tc4 = s_c4[0][lane] + s_c4[1][lane] + s_c4[2][lane] + s_c4[3][lane] + b4[0];
    const float tcs = s_cs[0][lane] + s_cs[1][lane] + s_cs[2][lane] + s_cs[3][lane];
    const float mask = 1.f / (1.f + expf(-tc4));
    colbuf[n] = tcs * (1.f + mask) * (1.f / (float)L_DIM);
  }
}

// ---------------- Stage 3: broadcast to all nodes --------------------------
__global__ __launch_bounds__(256) void k_broadcast(
    const float* __restrict__ colbuf, float4* __restrict__ out)
{
  const size_t idx = (size_t)blockIdx.x * 256 + threadIdx.x; // float4 index
  const int nq = (int)(idx & 255);
  const float4 v = *(const float4*)(colbuf + nq * 4);
  out[idx] = v;
}

extern "C" void kernel_launch(void* const* d_in, const int* in_sizes, int n_in,
                              void* d_out, int out_size, void* d_ws, size_t ws_size,
                              hipStream_t stream) {
  // inputs: x, edge_index, edge_attr, conv3_w, conv3_b, conv4_w, conv4_b
  const float* edge_attr = (const float*)d_in[2];   // [8192][1024]
  const float* w3        = (const float*)d_in[3];   // [240][8192]
  const float* b3        = (const float*)d_in[4];   // [240]
  const float* w4        = (const float*)d_in[5];   // [240]
  const float* b4        = (const float*)d_in[6];   // [1]

  float* out = (float*)d_out;
  unsigned short* part = (unsigned short*)d_out;  // [32][240][1024] bf16 (7.86M elems)
  float* edge   = out + EDGE_OFF;                 // [240][1024] f32
  float* colbuf = (float*)d_ws;                   // [1024] f32

  k_gemm        <<<dim3(8, 32), 512, 0, stream>>>(w3, edge_attr, part);
  k_reduce      <<<dim3(960),   256, 0, stream>>>(part, b3, edge);
  k_mask_colsum <<<dim3(16),    256, 0, stream>>>(edge, w4, b4, colbuf);
  k_broadcast   <<<dim3(10000), 256, 0, stream>>>(colbuf, (float4*)out);
}

// Round 3
// 43.465 us; speedup vs baseline: 3.7831x; 1.2243x over previous
//
#include <hip/hip_runtime.h>
#include <hip/hip_bf16.h>

#define K_DIM 8192
#define L_DIM 1024
#define C2 240
#define MSTRIDE 256                 // padded m stride in partials
#define BM 128
#define BN 128
#define BK 64
#define KCHUNK 256
#define KSPLIT 32                   // 8192 / 256
#define NSTEP (KCHUNK / BK)         // 4
#define PART_KC (L_DIM * MSTRIDE)   // 262144 elems per k-chunk

typedef __attribute__((ext_vector_type(4))) float f32x4;
typedef __attribute__((ext_vector_type(8))) short bf16x8;
typedef __attribute__((ext_vector_type(4))) short bf16x4;

__device__ __forceinline__ unsigned short f2bf(float f) {
  return __builtin_bit_cast(unsigned short, __float2bfloat16(f));
}
__device__ __forceinline__ float bf2f(unsigned short h) {
  unsigned u = ((unsigned)h) << 16;
  return __builtin_bit_cast(float, u);
}

// ---------------- Stage 1: bf16 MFMA K-split GEMM --------------------------
// part[kc][n][m(pad 256)] = (W[240][8192] @ A[8192][1024]) k-chunk partials.
// 512 blocks x 256 thr (4 waves, 2m x 2n of 64x64). XCD-chunked remap:
// XCD x gets 4 consecutive k-chunks (all 16 m/n tiles) -> W + A L2-local.
__global__ __launch_bounds__(256) void k_gemm(
    const float* __restrict__ Wm, const float* __restrict__ Am,
    unsigned short* __restrict__ part)
{
  __shared__ __align__(16) unsigned short sW[BM * BK];  // [m][k^swz] 16 KB
  __shared__ __align__(16) unsigned short sA[BN * BK];  // [n][k^swz] 16 KB

  const int bid = blockIdx.x;
  const int wk  = (bid & 7) * 64 + (bid >> 3);  // bijective, 512 % 8 == 0
  const int nt8   = wk & 7;
  const int mtile = (wk >> 3) & 1;
  const int kc    = wk >> 4;

  const int t    = threadIdx.x;
  const int lane = t & 63;
  const int wid  = t >> 6;
  const int mg   = wid & 1;        // 64-row group
  const int ng   = wid >> 1;       // 64-col group
  const int l15  = lane & 15;
  const int lk8  = (lane >> 4) * 8;

  const int n0b = nt8 * BN;
  const int m0b = mtile * BM;
  const int k0  = kc * KCHUNK;

  // staging: W thread -> (row t>>1, k-half (t&1)*32); A -> (n-quad, k-oct)
  const int swm = t >> 1;
  const int swk = (t & 1) * 32;
  const int san = (t & 31) * 4;
  const int sak = (t >> 5) * 8;

  const float* wp = Wm + (size_t)(m0b + swm) * K_DIM + k0 + swk;
  const float* ap = Am + (size_t)(k0 + sak) * L_DIM + n0b + san;
  const bool wok = (m0b + swm) < C2;

  f32x4 wreg[8], areg[8];
  f32x4 acc[4][4];
#pragma unroll
  for (int i = 0; i < 4; ++i)
#pragma unroll
    for (int j = 0; j < 4; ++j) acc[i][j] = (f32x4){0.f, 0.f, 0.f, 0.f};

  // prefetch step 0
#pragma unroll
  for (int j = 0; j < 8; ++j)
    wreg[j] = wok ? *(const f32x4*)(wp + 4 * j) : (f32x4){0.f, 0.f, 0.f, 0.f};
#pragma unroll
  for (int r = 0; r < 8; ++r)
    areg[r] = *(const f32x4*)(ap + (size_t)r * L_DIM);

  for (int s = 0; s < NSTEP; ++s) {
    // ---- convert (v_cvt_pk_bf16_f32 via cast) + swizzled LDS write ----
#pragma unroll
    for (int j = 0; j < 4; ++j) {
      f32x4 a = wreg[2 * j], b = wreg[2 * j + 1];
      bf16x8 v;
      v[0] = (short)f2bf(a[0]); v[1] = (short)f2bf(a[1]);
      v[2] = (short)f2bf(a[2]); v[3] = (short)f2bf(a[3]);
      v[4] = (short)f2bf(b[0]); v[5] = (short)f2bf(b[1]);
      v[6] = (short)f2bf(b[2]); v[7] = (short)f2bf(b[3]);
      *(bf16x8*)&sW[swm * BK + ((swk + 8 * j) ^ ((swm & 7) << 3))] = v;
    }
#pragma unroll
    for (int j = 0; j < 4; ++j) {
      int n = san + j;
      bf16x8 v;
#pragma unroll
      for (int r = 0; r < 8; ++r) v[r] = (short)f2bf(areg[r][j]);
      *(bf16x8*)&sA[n * BK + (sak ^ ((n & 7) << 3))] = v;
    }
    __syncthreads();

    // ---- issue next step's global loads (overlap with MFMA below) ----
    if (s + 1 < NSTEP) {
      const float* wp2 = wp + (s + 1) * BK;
      const float* ap2 = ap + (size_t)(s + 1) * BK * L_DIM;
#pragma unroll
      for (int j = 0; j < 8; ++j)
        wreg[j] = wok ? *(const f32x4*)(wp2 + 4 * j) : (f32x4){0.f, 0.f, 0.f, 0.f};
#pragma unroll
      for (int r = 0; r < 8; ++r)
        areg[r] = *(const f32x4*)(ap2 + (size_t)r * L_DIM);
    }

    // ---- compute from LDS ----
#pragma unroll
    for (int kk = 0; kk < BK; kk += 32) {
      bf16x8 wf[4], af[4];
#pragma unroll
      for (int mt = 0; mt < 4; ++mt) {
        int m = mg * 64 + mt * 16 + l15;
        wf[mt] = *(const bf16x8*)&sW[m * BK + ((kk + lk8) ^ ((m & 7) << 3))];
      }
#pragma unroll
      for (int nt = 0; nt < 4; ++nt) {
        int n = ng * 64 + nt * 16 + l15;
        af[nt] = *(const bf16x8*)&sA[n * BK + ((kk + lk8) ^ ((n & 7) << 3))];
      }
#pragma unroll
      for (int mt = 0; mt < 4; ++mt)
#pragma unroll
        for (int nt = 0; nt < 4; ++nt)
          acc[mt][nt] = __builtin_amdgcn_mfma_f32_16x16x32_bf16(
              wf[mt], af[nt], acc[mt][nt], 0, 0, 0);
    }
    __syncthreads();
  }

  // ---- store transposed bf16 partials: part[kc][n][m], 8B per lane ----
  unsigned short* pb = part + (size_t)kc * PART_KC;
#pragma unroll
  for (int mt = 0; mt < 4; ++mt) {
    const int m0 = m0b + mg * 64 + mt * 16 + (lane >> 4) * 4;
#pragma unroll
    for (int nt = 0; nt < 4; ++nt) {
      const int n = n0b + ng * 64 + nt * 16 + l15;
      bf16x4 v;
      v[0] = (short)f2bf(acc[mt][nt][0]);
      v[1] = (short)f2bf(acc[mt][nt][1]);
      v[2] = (short)f2bf(acc[mt][nt][2]);
      v[3] = (short)f2bf(acc[mt][nt][3]);
      *(bf16x4*)&pb[(size_t)n * MSTRIDE + m0] = v;
    }
  }
}

// ---------------- Stage 2: kc-reduce + bias + ReLU + both m-reductions -----
// One block per column n: thread t = m. Reads coalesced (m contiguous).
__global__ __launch_bounds__(256) void k_colbuf(
    const unsigned short* __restrict__ part, const float* __restrict__ b3,
    const float* __restrict__ w4, const float* __restrict__ b4,
    float* __restrict__ colbuf)
{
  __shared__ float red[2][4];
  const int n = blockIdx.x;
  const int t = threadIdx.x;
  const unsigned short* p = part + (size_t)n * MSTRIDE + t;
  float s = 0.f;
#pragma unroll
  for (int kcc = 0; kcc < KSPLIT; ++kcc)
    s += bf2f(p[(size_t)kcc * PART_KC]);
  float e = 0.f, c4 = 0.f;
  if (t < C2) {
    e  = fmaxf(s + b3[t], 0.f);
    c4 = w4[t] * e;
  }
#pragma unroll
  for (int off = 32; off; off >>= 1) {
    e  += __shfl_xor(e, off);
    c4 += __shfl_xor(c4, off);
  }
  const int wv = t >> 6;
  if ((t & 63) == 0) { red[0][wv] = e; red[1][wv] = c4; }
  __syncthreads();
  if (t == 0) {
    const float cs  = red[0][0] + red[0][1] + red[0][2] + red[0][3];
    const float tc4 = red[1][0] + red[1][1] + red[1][2] + red[1][3] + b4[0];
    const float mask = 1.f / (1.f + expf(-tc4));
    colbuf[n] = cs * (1.f + mask) * (1.f / (float)L_DIM);
  }
}

// ---------------- Stage 3: broadcast to all nodes --------------------------
__global__ __launch_bounds__(256) void k_broadcast(
    const float* __restrict__ colbuf, float4* __restrict__ out)
{
  const size_t idx = (size_t)blockIdx.x * 256 + threadIdx.x;  // float4 index
  const int nq = (int)(idx & 255);
  const float4 v = *(const float4*)(colbuf + nq * 4);
  out[idx] = v;
}

extern "C" void kernel_launch(void* const* d_in, const int* in_sizes, int n_in,
                              void* d_out, int out_size, void* d_ws, size_t ws_size,
                              hipStream_t stream) {
  // inputs: x, edge_index, edge_attr, conv3_w, conv3_b, conv4_w, conv4_b
  const float* edge_attr = (const float*)d_in[2];   // [8192][1024]
  const float* w3        = (const float*)d_in[3];   // [240][8192]
  const float* b3        = (const float*)d_in[4];   // [240]
  const float* w4        = (const float*)d_in[5];   // [240]
  const float* b4        = (const float*)d_in[6];   // [1]

  float* out = (float*)d_out;
  unsigned short* part = (unsigned short*)d_out;  // [32][1024][256] bf16 = 16.8 MB
  float* colbuf = (float*)d_ws;                   // [1024] f32

  k_gemm      <<<dim3(512),   256, 0, stream>>>(w3, edge_attr, part);
  k_colbuf    <<<dim3(1024),  256, 0, stream>>>(part, b3, w4, b4, colbuf);
  k_broadcast <<<dim3(10000), 256, 0, stream>>>(colbuf, (float4*)out);
}